// Round 1
// baseline (425.054 us; speedup 1.0000x reference)
//
#include <hip/hip_runtime.h>

typedef __bf16 bf16;
typedef __attribute__((ext_vector_type(8))) __bf16 bf16x8;
typedef __attribute__((ext_vector_type(4))) float f32x4;
typedef __attribute__((ext_vector_type(4))) _Float16 f16x4;

#define B_   2
#define L_   1024
#define DM_  512
#define H_   8
#define D_   64
#define PD_  64
#define NEG_VAL -10000.0f

#define XB_N   (2048*512)
#define WT_N   (1536*512)
#define WTO_N  (512*512)
#define WTPB_N (16*64)

static __device__ __forceinline__ f32x4 mfma_bf16(bf16x8 a, bf16x8 b, f32x4 c) {
  return __builtin_amdgcn_mfma_f32_16x16x32_bf16(a, b, c, 0, 0, 0);
}

// ---------------- prep: convert & transpose weights, convert x ----------------
__global__ __launch_bounds__(256) void prep_kernel(
    const float* __restrict__ x, const float* __restrict__ Wq, const float* __restrict__ Wk,
    const float* __restrict__ Wv, const float* __restrict__ Wo, const float* __restrict__ Wpb,
    bf16* __restrict__ xb, bf16* __restrict__ Wt, bf16* __restrict__ Wto, bf16* __restrict__ Wtpb) {
  const int total = XB_N + WT_N + WTO_N + WTPB_N;
  for (int idx = blockIdx.x * 256 + threadIdx.x; idx < total; idx += gridDim.x * 256) {
    if (idx < XB_N) {
      xb[idx] = (bf16)x[idx];
    } else if (idx < XB_N + WT_N) {
      int t = idx - XB_N;
      int n = t >> 9, kk = t & 511;       // Wt[n][k], n in [0,1536)
      int sel = n >> 9, nn = n & 511;
      const float* W = sel == 0 ? Wq : (sel == 1 ? Wk : Wv);
      Wt[t] = (bf16)W[kk * 512 + nn];
    } else if (idx < XB_N + WT_N + WTO_N) {
      int t = idx - XB_N - WT_N;
      int n = t >> 9, kk = t & 511;
      Wto[t] = (bf16)Wo[kk * 512 + n];
    } else {
      int t = idx - XB_N - WT_N - WTO_N;
      int n = t >> 6, kk = t & 63;        // Wtpb[n][k], n in [0,16), k in [0,64)
      Wtpb[t] = (n < 8) ? (bf16)Wpb[kk * 8 + n] : (bf16)0.0f;
    }
  }
}

// ---------------- qkv: xb(2048x512) @ Wt^T(512x1536) -> q,k,v fp32 [b][h][l][d] ----------------
__global__ __launch_bounds__(256) void qkv_gemm(
    const bf16* __restrict__ xb, const bf16* __restrict__ Wt,
    const float* __restrict__ bq, const float* __restrict__ bk, const float* __restrict__ bv,
    float* __restrict__ q, float* __restrict__ k, float* __restrict__ v) {
  int wid = blockIdx.x * 4 + (threadIdx.x >> 6);
  int lane = threadIdx.x & 63;
  int mt = wid / 96, nt = wid - mt * 96;   // 128 x 96 tiles of 16x16
  int row0 = mt * 16, col0 = nt * 16;
  int lr = lane & 15, lg = lane >> 4;
  const bf16* arow = xb + (row0 + lr) * 512;
  const bf16* brow = Wt + (col0 + lr) * 512;
  f32x4 acc = {0.f, 0.f, 0.f, 0.f};
#pragma unroll
  for (int kk = 0; kk < 512; kk += 32) {
    bf16x8 a = *reinterpret_cast<const bf16x8*>(arow + kk + lg * 8);
    bf16x8 b = *reinterpret_cast<const bf16x8*>(brow + kk + lg * 8);
    acc = mfma_bf16(a, b, acc);
  }
  int col = col0 + lr;
  int wsel = col >> 9;
  int ncol = col & 511;
  int h = ncol >> 6, d = ncol & 63;
  const float* bias = wsel == 0 ? bq : (wsel == 1 ? bk : bv);
  float* dst = wsel == 0 ? q : (wsel == 1 ? k : v);
  float bval = bias[ncol];
#pragma unroll
  for (int r = 0; r < 4; ++r) {
    int m = row0 + lg * 4 + r;
    int bidx = m >> 10, l = m & 1023;
    dst[(((bidx * H_ + h) * L_ + l) * D_) + d] = acc[r] + bval;
  }
}

// ---------------- bias: z(2M x 64) @ Wtpb^T(64 x 16, 8 used) -> bias fp16 [b][h][i][j] ----------------
__global__ __launch_bounds__(256) void bias_gemm(
    const float* __restrict__ z, const bf16* __restrict__ Wtpb, _Float16* __restrict__ biasbuf) {
  int wid = blockIdx.x * 4 + (threadIdx.x >> 6);
  int lane = threadIdx.x & 63;
  int lr = lane & 15, lg = lane >> 4;
  long p0 = (long)wid * 16;                 // pair base, pairs = (b*L + i)*L + j
  const float* zr = z + (p0 + lr) * 64;
  f32x4 z0 = *reinterpret_cast<const f32x4*>(zr + lg * 8);
  f32x4 z1 = *reinterpret_cast<const f32x4*>(zr + lg * 8 + 4);
  f32x4 z2 = *reinterpret_cast<const f32x4*>(zr + 32 + lg * 8);
  f32x4 z3 = *reinterpret_cast<const f32x4*>(zr + 32 + lg * 8 + 4);
  bf16x8 a0, a1;
#pragma unroll
  for (int e = 0; e < 4; ++e) { a0[e] = (bf16)z0[e]; a0[e + 4] = (bf16)z1[e]; }
#pragma unroll
  for (int e = 0; e < 4; ++e) { a1[e] = (bf16)z2[e]; a1[e + 4] = (bf16)z3[e]; }
  bf16x8 b0 = *reinterpret_cast<const bf16x8*>(Wtpb + lr * 64 + lg * 8);
  bf16x8 b1 = *reinterpret_cast<const bf16x8*>(Wtpb + lr * 64 + 32 + lg * 8);
  f32x4 acc = {0.f, 0.f, 0.f, 0.f};
  acc = mfma_bf16(a0, b0, acc);
  acc = mfma_bf16(a1, b1, acc);
  if (lr < 8) {
    int h = lr;
    int bidx = (int)(p0 >> 20);
    int i = ((int)(p0 >> 10)) & 1023;
    int j = ((int)p0 & 1023) + lg * 4;
    _Float16* dst = biasbuf + ((((long)bidx * H_ + h) * L_ + i) << 10) + j;
    f16x4 hv;
#pragma unroll
    for (int r = 0; r < 4; ++r) hv[r] = (_Float16)acc[r];
    *reinterpret_cast<f16x4*>(dst) = hv;
  }
}

// ---------------- attention: flash-style, VALU, per (b,h,32-row i-tile) ----------------
__global__ __launch_bounds__(256) void attn_kernel(
    const float* __restrict__ q, const float* __restrict__ k, const float* __restrict__ v,
    const _Float16* __restrict__ biasbuf, const int* __restrict__ mask, bf16* __restrict__ attn_out) {
  __shared__ float q_lds[32][64];      // [i][d], pre-scaled by 1/8
  __shared__ float k_lds[64][64];      // transposed: [d][j]
  __shared__ float v_lds[64][64];      // [j][d]
  __shared__ float p_lds[4][8][64];    // per-wave [i][j]
  int bid = blockIdx.x;
  int b = bid >> 8;
  int h = (bid >> 5) & 7;
  int it = bid & 31;
  int i0 = it * 32;
  int tid = threadIdx.x, w = tid >> 6, lane = tid & 63;
  const float* qbase = q + (((long)(b * H_ + h)) * L_ + i0) * D_;
  const float* kbase = k + (((long)(b * H_ + h)) * L_) * D_;
  const float* vbase = v + (((long)(b * H_ + h)) * L_) * D_;
  // load q tile (32x64): thread t -> row t>>3, d-block (t&7)*8
  {
    int row = tid >> 3, dblk = (tid & 7) * 8;
    const float* qp = qbase + row * 64 + dblk;
    f32x4 q0 = *reinterpret_cast<const f32x4*>(qp);
    f32x4 q1 = *reinterpret_cast<const f32x4*>(qp + 4);
#pragma unroll
    for (int e = 0; e < 4; ++e) { q_lds[row][dblk + e] = q0[e] * 0.125f; q_lds[row][dblk + 4 + e] = q1[e] * 0.125f; }
  }
  int ibase = w * 8;
  bool qok[8];
#pragma unroll
  for (int i = 0; i < 8; ++i) qok[i] = mask[b * L_ + i0 + ibase + i] != 0;
  float m_i[8], l_i[8], o_i[8];
#pragma unroll
  for (int i = 0; i < 8; ++i) { m_i[i] = -3.0e38f; l_i[i] = 0.f; o_i[i] = 0.f; }
  const _Float16* biasbase = biasbuf + (((long)(b * H_ + h)) * L_ + i0) * L_;
  for (int jt = 0; jt < 16; ++jt) {
    int j0 = jt * 64;
    __syncthreads();
    {
      int row = tid >> 2, dblk = (tid & 3) * 16;
      const float* kp = kbase + (j0 + row) * 64 + dblk;
      const float* vp = vbase + (j0 + row) * 64 + dblk;
#pragma unroll
      for (int c = 0; c < 4; ++c) {
        f32x4 kv = *reinterpret_cast<const f32x4*>(kp + c * 4);
        f32x4 vv = *reinterpret_cast<const f32x4*>(vp + c * 4);
#pragma unroll
        for (int e = 0; e < 4; ++e) {
          k_lds[dblk + c * 4 + e][row] = kv[e];
          v_lds[row][dblk + c * 4 + e] = vv[e];
        }
      }
    }
    __syncthreads();
    bool kok = mask[b * L_ + j0 + lane] != 0;
    float s[8];
#pragma unroll
    for (int i = 0; i < 8; ++i) s[i] = (float)biasbase[(long)(ibase + i) * L_ + j0 + lane];
    for (int d4 = 0; d4 < 16; ++d4) {
      float k0 = k_lds[d4 * 4 + 0][lane];
      float k1 = k_lds[d4 * 4 + 1][lane];
      float k2 = k_lds[d4 * 4 + 2][lane];
      float k3 = k_lds[d4 * 4 + 3][lane];
#pragma unroll
      for (int i = 0; i < 8; ++i) {
        float4 qv = *reinterpret_cast<const float4*>(&q_lds[ibase + i][d4 * 4]);
        s[i] += qv.x * k0 + qv.y * k1 + qv.z * k2 + qv.w * k3;
      }
    }
#pragma unroll
    for (int i = 0; i < 8; ++i) {
      float sv = s[i];
      if (!kok) sv = NEG_VAL;
      if (!qok[i]) sv = NEG_VAL;
      float mx = sv;
#pragma unroll
      for (int off = 32; off >= 1; off >>= 1) mx = fmaxf(mx, __shfl_xor(mx, off));
      float mnew = fmaxf(m_i[i], mx);
      float p = __expf(sv - mnew);
      float ps = p;
#pragma unroll
      for (int off = 32; off >= 1; off >>= 1) ps += __shfl_xor(ps, off);
      float alpha = __expf(m_i[i] - mnew);
      l_i[i] = l_i[i] * alpha + ps;
      m_i[i] = mnew;
      o_i[i] *= alpha;
      p_lds[w][i][lane] = p;
    }
    for (int j4 = 0; j4 < 16; ++j4) {
      float v0 = v_lds[j4 * 4 + 0][lane];
      float v1 = v_lds[j4 * 4 + 1][lane];
      float v2 = v_lds[j4 * 4 + 2][lane];
      float v3 = v_lds[j4 * 4 + 3][lane];
#pragma unroll
      for (int i = 0; i < 8; ++i) {
        float4 pv = *reinterpret_cast<const float4*>(&p_lds[w][i][j4 * 4]);
        o_i[i] += pv.x * v0 + pv.y * v1 + pv.z * v2 + pv.w * v3;
      }
    }
  }
#pragma unroll
  for (int i = 0; i < 8; ++i) {
    int ig = i0 + ibase + i;
    attn_out[((long)(b * L_ + ig)) * DM_ + h * D_ + lane] = (bf16)(o_i[i] / l_i[i]);
  }
}

// ---------------- out: attn_out(2048x512) @ Wto^T -> d_out fp32 + bo ----------------
__global__ __launch_bounds__(256) void out_gemm(
    const bf16* __restrict__ ab, const bf16* __restrict__ Wto,
    const float* __restrict__ bo, float* __restrict__ out) {
  int wid = blockIdx.x * 4 + (threadIdx.x >> 6);
  int lane = threadIdx.x & 63;
  int mt = wid >> 5, nt = wid & 31;
  int row0 = mt * 16, col0 = nt * 16;
  int lr = lane & 15, lg = lane >> 4;
  const bf16* arow = ab + (row0 + lr) * 512;
  const bf16* brow = Wto + (col0 + lr) * 512;
  f32x4 acc = {0.f, 0.f, 0.f, 0.f};
#pragma unroll
  for (int kk = 0; kk < 512; kk += 32) {
    bf16x8 a = *reinterpret_cast<const bf16x8*>(arow + kk + lg * 8);
    bf16x8 b = *reinterpret_cast<const bf16x8*>(brow + kk + lg * 8);
    acc = mfma_bf16(a, b, acc);
  }
  int col = col0 + lr;
  float bval = bo[col];
#pragma unroll
  for (int r = 0; r < 4; ++r) {
    int m = row0 + lg * 4 + r;
    out[(long)m * 512 + col] = acc[r] + bval;
  }
}

extern "C" void kernel_launch(void* const* d_in, const int* in_sizes, int n_in,
                              void* d_out, int out_size, void* d_ws, size_t ws_size,
                              hipStream_t stream) {
  const float* x    = (const float*)d_in[0];
  const float* z    = (const float*)d_in[1];
  const int*   mask = (const int*)d_in[2];
  const float* Wq   = (const float*)d_in[3];
  const float* bq   = (const float*)d_in[4];
  const float* Wk   = (const float*)d_in[5];
  const float* bk   = (const float*)d_in[6];
  const float* Wv   = (const float*)d_in[7];
  const float* bv   = (const float*)d_in[8];
  const float* Wo   = (const float*)d_in[9];
  const float* bo   = (const float*)d_in[10];
  const float* Wpb  = (const float*)d_in[11];

  char* ws = (char*)d_ws;
  bf16* xb        = (bf16*)(ws + 0);                    // 2,097,152
  bf16* Wt        = (bf16*)(ws + 2097152);              // 1,572,864
  bf16* Wto       = (bf16*)(ws + 3670016);              //   524,288
  bf16* Wtpb      = (bf16*)(ws + 4194304);              //     2,048
  float* qb       = (float*)(ws + 4196352);             // 4,194,304
  float* kb       = (float*)(ws + 8390656);             // 4,194,304
  float* vb       = (float*)(ws + 12584960);            // 4,194,304
  bf16* attn_out  = (bf16*)(ws + 16779264);             // 2,097,152
  _Float16* biasb = (_Float16*)(ws + 18876416);         // 33,554,432  -> total ~50 MB

  prep_kernel<<<2048, 256, 0, stream>>>(x, Wq, Wk, Wv, Wo, Wpb, xb, Wt, Wto, Wtpb);
  qkv_gemm<<<3072, 256, 0, stream>>>(xb, Wt, bq, bk, bv, qb, kb, vb);
  bias_gemm<<<32768, 256, 0, stream>>>(z, Wtpb, biasb);
  attn_kernel<<<512, 256, 0, stream>>>(qb, kb, vb, biasb, mask, attn_out);
  out_gemm<<<1024, 256, 0, stream>>>(attn_out, Wto, bo, (float*)d_out);
}

// Round 2
// 212.703 us; speedup vs baseline: 1.9983x; 1.9983x over previous
//
#include <hip/hip_runtime.h>

typedef __bf16 bf16;
typedef __attribute__((ext_vector_type(4))) __bf16 bf16x4;
typedef __attribute__((ext_vector_type(8))) __bf16 bf16x8;
typedef __attribute__((ext_vector_type(4))) float f32x4;
typedef __attribute__((ext_vector_type(4))) _Float16 f16x4;

#define B_   2
#define L_   1024
#define DM_  512
#define H_   8
#define D_   64
#define PD_  64
#define NEG_VAL -10000.0f

#define XB_N   (2048*512)
#define WT_N   (1536*512)
#define WTO_N  (512*512)
#define WTPB_N (16*64)

static __device__ __forceinline__ f32x4 mfma_bf16(bf16x8 a, bf16x8 b, f32x4 c) {
  return __builtin_amdgcn_mfma_f32_16x16x32_bf16(a, b, c, 0, 0, 0);
}

// ---------------- prep: convert & transpose weights, convert x ----------------
__global__ __launch_bounds__(256) void prep_kernel(
    const float* __restrict__ x, const float* __restrict__ Wq, const float* __restrict__ Wk,
    const float* __restrict__ Wv, const float* __restrict__ Wo, const float* __restrict__ Wpb,
    bf16* __restrict__ xb, bf16* __restrict__ Wt, bf16* __restrict__ Wto, bf16* __restrict__ Wtpb) {
  const int total = XB_N + WT_N + WTO_N + WTPB_N;
  for (int idx = blockIdx.x * 256 + threadIdx.x; idx < total; idx += gridDim.x * 256) {
    if (idx < XB_N) {
      xb[idx] = (bf16)x[idx];
    } else if (idx < XB_N + WT_N) {
      int t = idx - XB_N;
      int n = t >> 9, kk = t & 511;       // Wt[n][k]
      int sel = n >> 9, nn = n & 511;
      const float* W = sel == 0 ? Wq : (sel == 1 ? Wk : Wv);
      Wt[t] = (bf16)W[kk * 512 + nn];
    } else if (idx < XB_N + WT_N + WTO_N) {
      int t = idx - XB_N - WT_N;
      int n = t >> 9, kk = t & 511;
      Wto[t] = (bf16)Wo[kk * 512 + n];
    } else {
      int t = idx - XB_N - WT_N - WTO_N;
      int n = t >> 6, kk = t & 63;
      Wtpb[t] = (n < 8) ? (bf16)Wpb[kk * 8 + n] : (bf16)0.0f;
    }
  }
}

// ---------------- qkv: xb(2048x512) @ Wt^T -> q,k bf16 [b][h][l][d], vT bf16 [b][h][d][l] ----------------
__global__ __launch_bounds__(256) void qkv_gemm(
    const bf16* __restrict__ xb, const bf16* __restrict__ Wt,
    const float* __restrict__ bq, const float* __restrict__ bk, const float* __restrict__ bv,
    bf16* __restrict__ qb, bf16* __restrict__ kb, bf16* __restrict__ vT) {
  int wid = blockIdx.x * 4 + (threadIdx.x >> 6);
  int lane = threadIdx.x & 63;
  int mt = wid / 48, nt = wid - mt * 48;   // 64 x 48 tiles of 32x32
  int row0 = mt * 32, col0 = nt * 32;
  int lr = lane & 15, lg = lane >> 4;
  const bf16* a0p = xb + (row0 + lr) * 512 + lg * 8;
  const bf16* a1p = a0p + 16 * 512;
  const bf16* b0p = Wt + (col0 + lr) * 512 + lg * 8;
  const bf16* b1p = b0p + 16 * 512;
  f32x4 acc00 = {0.f,0.f,0.f,0.f}, acc01 = acc00, acc10 = acc00, acc11 = acc00;
#pragma unroll
  for (int kk = 0; kk < 512; kk += 32) {
    bf16x8 a0 = *reinterpret_cast<const bf16x8*>(a0p + kk);
    bf16x8 a1 = *reinterpret_cast<const bf16x8*>(a1p + kk);
    bf16x8 b0 = *reinterpret_cast<const bf16x8*>(b0p + kk);
    bf16x8 b1 = *reinterpret_cast<const bf16x8*>(b1p + kk);
    acc00 = mfma_bf16(a0, b0, acc00);
    acc01 = mfma_bf16(a0, b1, acc01);
    acc10 = mfma_bf16(a1, b0, acc10);
    acc11 = mfma_bf16(a1, b1, acc11);
  }
#pragma unroll
  for (int ni = 0; ni < 2; ++ni) {
    int col = col0 + ni * 16 + lr;
    int wsel = col >> 9;
    int ncol = col & 511;
    int h = ncol >> 6, d = ncol & 63;
    const float* bias = wsel == 0 ? bq : (wsel == 1 ? bk : bv);
    float bval = bias[ncol];
#pragma unroll
    for (int mi = 0; mi < 2; ++mi) {
      f32x4 acc = (mi == 0) ? (ni == 0 ? acc00 : acc01) : (ni == 0 ? acc10 : acc11);
      int m0 = row0 + mi * 16 + lg * 4;
      int bidx = m0 >> 10, l0 = m0 & 1023;
      if (wsel == 2) {
        bf16x4 pv;
#pragma unroll
        for (int r = 0; r < 4; ++r) pv[r] = (bf16)(acc[r] + bval);
        *reinterpret_cast<bf16x4*>(vT + ((long)(bidx * H_ + h) * D_ + d) * L_ + l0) = pv;
      } else if (wsel == 0) {
#pragma unroll
        for (int r = 0; r < 4; ++r)
          qb[((long)(bidx * H_ + h) * L_ + l0 + r) * D_ + d] = (bf16)((acc[r] + bval) * 0.125f);
      } else {
#pragma unroll
        for (int r = 0; r < 4; ++r)
          kb[((long)(bidx * H_ + h) * L_ + l0 + r) * D_ + d] = (bf16)(acc[r] + bval);
      }
    }
  }
}

// ---------------- bias: z(2M x 64) @ Wtpb^T -> bias fp16 [b][h][i][j] ----------------
__global__ __launch_bounds__(256) void bias_gemm(
    const float* __restrict__ z, const bf16* __restrict__ Wtpb, _Float16* __restrict__ biasbuf) {
  int wid = blockIdx.x * 4 + (threadIdx.x >> 6);
  int lane = threadIdx.x & 63;
  int lr = lane & 15, lg = lane >> 4;
  long p0 = (long)wid * 16;
  const float* zr = z + (p0 + lr) * 64;
  f32x4 z0 = *reinterpret_cast<const f32x4*>(zr + lg * 8);
  f32x4 z1 = *reinterpret_cast<const f32x4*>(zr + lg * 8 + 4);
  f32x4 z2 = *reinterpret_cast<const f32x4*>(zr + 32 + lg * 8);
  f32x4 z3 = *reinterpret_cast<const f32x4*>(zr + 32 + lg * 8 + 4);
  bf16x8 a0, a1;
#pragma unroll
  for (int e = 0; e < 4; ++e) { a0[e] = (bf16)z0[e]; a0[e + 4] = (bf16)z1[e]; }
#pragma unroll
  for (int e = 0; e < 4; ++e) { a1[e] = (bf16)z2[e]; a1[e + 4] = (bf16)z3[e]; }
  bf16x8 b0 = *reinterpret_cast<const bf16x8*>(Wtpb + lr * 64 + lg * 8);
  bf16x8 b1 = *reinterpret_cast<const bf16x8*>(Wtpb + lr * 64 + 32 + lg * 8);
  f32x4 acc = {0.f, 0.f, 0.f, 0.f};
  acc = mfma_bf16(a0, b0, acc);
  acc = mfma_bf16(a1, b1, acc);
  if (lr < 8) {
    int h = lr;
    int bidx = (int)(p0 >> 20);
    int i = ((int)(p0 >> 10)) & 1023;
    int j = ((int)p0 & 1023) + lg * 4;
    _Float16* dst = biasbuf + ((((long)bidx * H_ + h) * L_ + i) << 10) + j;
    f16x4 hv;
#pragma unroll
    for (int r = 0; r < 4; ++r) hv[r] = (_Float16)acc[r];
    *reinterpret_cast<f16x4*>(dst) = hv;
  }
}

// ---------------- attention: MFMA flash, block=(b,h,16 i-rows), 4 waves split j 4-way ----------------
__global__ __launch_bounds__(256) void attn_kernel(
    const bf16* __restrict__ qb, const bf16* __restrict__ kb, const bf16* __restrict__ vT,
    const _Float16* __restrict__ biasbuf, const int* __restrict__ mask, bf16* __restrict__ attn_out) {
  __shared__ bf16  p_lds[4][16][64];   // XOR-swizzled (byte ^= (row&7)<<4), 128B row stride
  __shared__ float o_lds[4][16][64];
  __shared__ float m_lds[4][16];
  __shared__ float l_lds[4][16];
  int bid = blockIdx.x;
  int b = bid >> 9, h = (bid >> 6) & 7, it = bid & 63;
  int i0 = it * 16;
  int tid = threadIdx.x, w = tid >> 6, lane = tid & 63, lr = lane & 15, lg = lane >> 4;

  const bf16* qrow = qb + ((long)(b * H_ + h) * L_ + i0 + lr) * D_ + lg * 8;
  bf16x8 qa0 = *reinterpret_cast<const bf16x8*>(qrow);
  bf16x8 qa1 = *reinterpret_cast<const bf16x8*>(qrow + 32);
  const bf16* kbase = kb + (long)(b * H_ + h) * L_ * D_;
  const bf16* vbase = vT + (long)(b * H_ + h) * D_ * L_;
  const _Float16* bias_base = biasbuf + ((long)(b * H_ + h) * L_ + i0) * L_;
  const int* mrow_mask = mask + b * L_;

  bool qok[4];
#pragma unroll
  for (int r = 0; r < 4; ++r) qok[r] = mrow_mask[i0 + lg * 4 + r] != 0;

  float mr[4] = {-3.0e38f, -3.0e38f, -3.0e38f, -3.0e38f};
  float lsum[4] = {0.f, 0.f, 0.f, 0.f};
  f32x4 o0 = {0.f,0.f,0.f,0.f}, o1 = o0, o2 = o0, o3 = o0;

  char* p_base = (char*)&p_lds[w][0][0];

  for (int jt = 0; jt < 4; ++jt) {
    int j0 = w * 256 + jt * 64;
    f32x4 s0, s1, s2, s3;
#pragma unroll
    for (int jsub = 0; jsub < 4; ++jsub) {
      int j = j0 + jsub * 16 + lr;
      f32x4 acc;
#pragma unroll
      for (int r = 0; r < 4; ++r) acc[r] = (float)bias_base[(long)(lg * 4 + r) * L_ + j];
      const bf16* kr = kbase + (long)j * D_ + lg * 8;
      acc = mfma_bf16(qa0, *reinterpret_cast<const bf16x8*>(kr), acc);
      acc = mfma_bf16(qa1, *reinterpret_cast<const bf16x8*>(kr + 32), acc);
      bool kok = mrow_mask[j] != 0;
      if (!kok) {
#pragma unroll
        for (int r = 0; r < 4; ++r) acc[r] = NEG_VAL;
      }
      if (jsub == 0) s0 = acc; else if (jsub == 1) s1 = acc; else if (jsub == 2) s2 = acc; else s3 = acc;
    }
#pragma unroll
    for (int r = 0; r < 4; ++r) {
      if (!qok[r]) { s0[r] = NEG_VAL; s1[r] = NEG_VAL; s2[r] = NEG_VAL; s3[r] = NEG_VAL; }
    }
#pragma unroll
    for (int r = 0; r < 4; ++r) {
      float mt_ = fmaxf(fmaxf(s0[r], s1[r]), fmaxf(s2[r], s3[r]));
#pragma unroll
      for (int off = 1; off <= 8; off <<= 1) mt_ = fmaxf(mt_, __shfl_xor(mt_, off));
      float mnew = fmaxf(mr[r], mt_);
      float alpha = __expf(mr[r] - mnew);
      mr[r] = mnew;
      float p0 = __expf(s0[r] - mnew);
      float p1 = __expf(s1[r] - mnew);
      float p2 = __expf(s2[r] - mnew);
      float p3 = __expf(s3[r] - mnew);
      float ps = p0 + p1 + p2 + p3;
#pragma unroll
      for (int off = 1; off <= 8; off <<= 1) ps += __shfl_xor(ps, off);
      lsum[r] = lsum[r] * alpha + ps;
      o0[r] *= alpha; o1[r] *= alpha; o2[r] *= alpha; o3[r] *= alpha;
      int row = lg * 4 + r;
      int sw = (row & 7) << 4;
      *(bf16*)(p_base + row * 128 + ((lr * 2) ^ sw)) = (bf16)p0;
      *(bf16*)(p_base + row * 128 + ((32 + lr * 2) ^ sw)) = (bf16)p1;
      *(bf16*)(p_base + row * 128 + ((64 + lr * 2) ^ sw)) = (bf16)p2;
      *(bf16*)(p_base + row * 128 + ((96 + lr * 2) ^ sw)) = (bf16)p3;
    }
    int swr = (lr & 7) << 4;
    bf16x8 pa0 = *(const bf16x8*)(p_base + lr * 128 + ((lg * 16) ^ swr));
    bf16x8 pa1 = *(const bf16x8*)(p_base + lr * 128 + ((64 + lg * 16) ^ swr));
#pragma unroll
    for (int dsub = 0; dsub < 4; ++dsub) {
      const bf16* vr = vbase + (long)(dsub * 16 + lr) * L_ + j0 + lg * 8;
      bf16x8 vb0 = *reinterpret_cast<const bf16x8*>(vr);
      bf16x8 vb1 = *reinterpret_cast<const bf16x8*>(vr + 32);
      f32x4 acc = (dsub == 0) ? o0 : (dsub == 1) ? o1 : (dsub == 2) ? o2 : o3;
      acc = mfma_bf16(pa0, vb0, acc);
      acc = mfma_bf16(pa1, vb1, acc);
      if (dsub == 0) o0 = acc; else if (dsub == 1) o1 = acc; else if (dsub == 2) o2 = acc; else o3 = acc;
    }
  }
#pragma unroll
  for (int r = 0; r < 4; ++r) {
    int row = lg * 4 + r;
    o_lds[w][row][0 * 16 + lr] = o0[r];
    o_lds[w][row][1 * 16 + lr] = o1[r];
    o_lds[w][row][2 * 16 + lr] = o2[r];
    o_lds[w][row][3 * 16 + lr] = o3[r];
    if (lr == 0) { m_lds[w][row] = mr[r]; l_lds[w][row] = lsum[r]; }
  }
  __syncthreads();
  {
    int row = tid >> 4, d0 = (tid & 15) * 4;
    float M = fmaxf(fmaxf(m_lds[0][row], m_lds[1][row]), fmaxf(m_lds[2][row], m_lds[3][row]));
    float lt = 0.f;
    float oacc[4] = {0.f, 0.f, 0.f, 0.f};
#pragma unroll
    for (int ww = 0; ww < 4; ++ww) {
      float c = __expf(m_lds[ww][row] - M);
      lt += c * l_lds[ww][row];
#pragma unroll
      for (int e = 0; e < 4; ++e) oacc[e] += c * o_lds[ww][row][d0 + e];
    }
    float inv = 1.0f / lt;
    bf16x4 ov;
#pragma unroll
    for (int e = 0; e < 4; ++e) ov[e] = (bf16)(oacc[e] * inv);
    *reinterpret_cast<bf16x4*>(attn_out + ((long)(b * L_ + i0 + row)) * DM_ + h * D_ + d0) = ov;
  }
}

// ---------------- out: attn_out(2048x512) @ Wto^T -> d_out fp32 + bo ----------------
__global__ __launch_bounds__(256) void out_gemm(
    const bf16* __restrict__ ab, const bf16* __restrict__ Wto,
    const float* __restrict__ bo, float* __restrict__ out) {
  int wid = blockIdx.x * 4 + (threadIdx.x >> 6);
  int lane = threadIdx.x & 63;
  int mt = wid >> 4, nt = wid & 15;    // 64 x 16 tiles of 32x32
  int row0 = mt * 32, col0 = nt * 32;
  int lr = lane & 15, lg = lane >> 4;
  const bf16* a0p = ab + (row0 + lr) * 512 + lg * 8;
  const bf16* a1p = a0p + 16 * 512;
  const bf16* b0p = Wto + (col0 + lr) * 512 + lg * 8;
  const bf16* b1p = b0p + 16 * 512;
  f32x4 acc00 = {0.f,0.f,0.f,0.f}, acc01 = acc00, acc10 = acc00, acc11 = acc00;
#pragma unroll
  for (int kk = 0; kk < 512; kk += 32) {
    bf16x8 a0 = *reinterpret_cast<const bf16x8*>(a0p + kk);
    bf16x8 a1 = *reinterpret_cast<const bf16x8*>(a1p + kk);
    bf16x8 b0 = *reinterpret_cast<const bf16x8*>(b0p + kk);
    bf16x8 b1 = *reinterpret_cast<const bf16x8*>(b1p + kk);
    acc00 = mfma_bf16(a0, b0, acc00);
    acc01 = mfma_bf16(a0, b1, acc01);
    acc10 = mfma_bf16(a1, b0, acc10);
    acc11 = mfma_bf16(a1, b1, acc11);
  }
#pragma unroll
  for (int ni = 0; ni < 2; ++ni) {
    int col = col0 + ni * 16 + lr;
    float bval = bo[col];
#pragma unroll
    for (int mi = 0; mi < 2; ++mi) {
      f32x4 acc = (mi == 0) ? (ni == 0 ? acc00 : acc01) : (ni == 0 ? acc10 : acc11);
      int m0 = row0 + mi * 16 + lg * 4;
#pragma unroll
      for (int r = 0; r < 4; ++r) out[(long)(m0 + r) * 512 + col] = acc[r] + bval;
    }
  }
}

extern "C" void kernel_launch(void* const* d_in, const int* in_sizes, int n_in,
                              void* d_out, int out_size, void* d_ws, size_t ws_size,
                              hipStream_t stream) {
  const float* x    = (const float*)d_in[0];
  const float* z    = (const float*)d_in[1];
  const int*   mask = (const int*)d_in[2];
  const float* Wq   = (const float*)d_in[3];
  const float* bq   = (const float*)d_in[4];
  const float* Wk   = (const float*)d_in[5];
  const float* bk   = (const float*)d_in[6];
  const float* Wv   = (const float*)d_in[7];
  const float* bv   = (const float*)d_in[8];
  const float* Wo   = (const float*)d_in[9];
  const float* bo   = (const float*)d_in[10];
  const float* Wpb  = (const float*)d_in[11];

  char* ws = (char*)d_ws;
  bf16* xb        = (bf16*)(ws + 0);                    // 2 MB
  bf16* Wt        = (bf16*)(ws + 2097152);              // 1.5 MB
  bf16* Wto       = (bf16*)(ws + 3670016);              // 0.5 MB
  bf16* Wtpb      = (bf16*)(ws + 4194304);              // 2 KB
  bf16* qbuf      = (bf16*)(ws + 4196352);              // 2 MB
  bf16* kbuf      = (bf16*)(ws + 6293504);              // 2 MB
  bf16* vTbuf     = (bf16*)(ws + 8390656);              // 2 MB
  bf16* attn_out  = (bf16*)(ws + 10487808);             // 2 MB
  _Float16* biasb = (_Float16*)(ws + 12584960);         // 33.5 MB

  prep_kernel<<<2048, 256, 0, stream>>>(x, Wq, Wk, Wv, Wo, Wpb, xb, Wt, Wto, Wtpb);
  qkv_gemm<<<768, 256, 0, stream>>>(xb, Wt, bq, bk, bv, qbuf, kbuf, vTbuf);
  bias_gemm<<<32768, 256, 0, stream>>>(z, Wtpb, biasb);
  attn_kernel<<<1024, 256, 0, stream>>>(qbuf, kbuf, vTbuf, biasb, mask, attn_out);
  out_gemm<<<256, 256, 0, stream>>>(attn_out, Wto, bo, (float*)d_out);
}

// Round 3
// 189.693 us; speedup vs baseline: 2.2407x; 1.1213x over previous
//
#include <hip/hip_runtime.h>

typedef __bf16 bf16;
typedef __attribute__((ext_vector_type(4))) __bf16 bf16x4;
typedef __attribute__((ext_vector_type(8))) __bf16 bf16x8;
typedef __attribute__((ext_vector_type(4))) float f32x4;

#define B_   2
#define L_   1024
#define DM_  512
#define H_   8
#define D_   64
#define PD_  64
#define NEG_VAL -10000.0f

#define XB_N   (2048*512)
#define WT_N   (1536*512)
#define WTO_N  (512*512)
#define WTPB_N (16*64)

static __device__ __forceinline__ f32x4 mfma_bf16(bf16x8 a, bf16x8 b, f32x4 c) {
  return __builtin_amdgcn_mfma_f32_16x16x32_bf16(a, b, c, 0, 0, 0);
}

// ---------------- prep: convert & transpose weights, convert x ----------------
__global__ __launch_bounds__(256) void prep_kernel(
    const float* __restrict__ x, const float* __restrict__ Wq, const float* __restrict__ Wk,
    const float* __restrict__ Wv, const float* __restrict__ Wo, const float* __restrict__ Wpb,
    bf16* __restrict__ xb, bf16* __restrict__ Wt, bf16* __restrict__ Wto, bf16* __restrict__ Wtpb) {
  const int total = XB_N + WT_N + WTO_N + WTPB_N;
  for (int idx = blockIdx.x * 256 + threadIdx.x; idx < total; idx += gridDim.x * 256) {
    if (idx < XB_N) {
      xb[idx] = (bf16)x[idx];
    } else if (idx < XB_N + WT_N) {
      int t = idx - XB_N;
      int n = t >> 9, kk = t & 511;       // Wt[n][k]
      int sel = n >> 9, nn = n & 511;
      const float* W = sel == 0 ? Wq : (sel == 1 ? Wk : Wv);
      Wt[t] = (bf16)W[kk * 512 + nn];
    } else if (idx < XB_N + WT_N + WTO_N) {
      int t = idx - XB_N - WT_N;
      int n = t >> 9, kk = t & 511;
      Wto[t] = (bf16)Wo[kk * 512 + n];
    } else {
      int t = idx - XB_N - WT_N - WTO_N;
      int n = t >> 6, kk = t & 63;
      Wtpb[t] = (n < 8) ? (bf16)Wpb[kk * 8 + n] : (bf16)0.0f;
    }
  }
}

// ---------------- qkv: xb(2048x512) @ Wt^T -> q,k bf16 [b][h][l][d], vT bf16 [b][h][d][l] ----------------
__global__ __launch_bounds__(256) void qkv_gemm(
    const bf16* __restrict__ xb, const bf16* __restrict__ Wt,
    const float* __restrict__ bq, const float* __restrict__ bk, const float* __restrict__ bv,
    bf16* __restrict__ qb, bf16* __restrict__ kb, bf16* __restrict__ vT) {
  int wid = blockIdx.x * 4 + (threadIdx.x >> 6);
  int lane = threadIdx.x & 63;
  int mt = wid / 48, nt = wid - mt * 48;   // 64 x 48 tiles of 32x32
  int row0 = mt * 32, col0 = nt * 32;
  int lr = lane & 15, lg = lane >> 4;
  const bf16* a0p = xb + (row0 + lr) * 512 + lg * 8;
  const bf16* a1p = a0p + 16 * 512;
  const bf16* b0p = Wt + (col0 + lr) * 512 + lg * 8;
  const bf16* b1p = b0p + 16 * 512;
  f32x4 acc00 = {0.f,0.f,0.f,0.f}, acc01 = acc00, acc10 = acc00, acc11 = acc00;
#pragma unroll
  for (int kk = 0; kk < 512; kk += 32) {
    bf16x8 a0 = *reinterpret_cast<const bf16x8*>(a0p + kk);
    bf16x8 a1 = *reinterpret_cast<const bf16x8*>(a1p + kk);
    bf16x8 b0 = *reinterpret_cast<const bf16x8*>(b0p + kk);
    bf16x8 b1 = *reinterpret_cast<const bf16x8*>(b1p + kk);
    acc00 = mfma_bf16(a0, b0, acc00);
    acc01 = mfma_bf16(a0, b1, acc01);
    acc10 = mfma_bf16(a1, b0, acc10);
    acc11 = mfma_bf16(a1, b1, acc11);
  }
#pragma unroll
  for (int ni = 0; ni < 2; ++ni) {
    int col = col0 + ni * 16 + lr;
    int wsel = col >> 9;
    int ncol = col & 511;
    int h = ncol >> 6, d = ncol & 63;
    const float* bias = wsel == 0 ? bq : (wsel == 1 ? bk : bv);
    float bval = bias[ncol];
#pragma unroll
    for (int mi = 0; mi < 2; ++mi) {
      f32x4 acc = (mi == 0) ? (ni == 0 ? acc00 : acc01) : (ni == 0 ? acc10 : acc11);
      int m0 = row0 + mi * 16 + lg * 4;
      int bidx = m0 >> 10, l0 = m0 & 1023;
      if (wsel == 2) {
        bf16x4 pv;
#pragma unroll
        for (int r = 0; r < 4; ++r) pv[r] = (bf16)(acc[r] + bval);
        *reinterpret_cast<bf16x4*>(vT + ((long)(bidx * H_ + h) * D_ + d) * L_ + l0) = pv;
      } else if (wsel == 0) {
#pragma unroll
        for (int r = 0; r < 4; ++r)
          qb[((long)(bidx * H_ + h) * L_ + l0 + r) * D_ + d] = (bf16)((acc[r] + bval) * 0.125f);
      } else {
#pragma unroll
        for (int r = 0; r < 4; ++r)
          kb[((long)(bidx * H_ + h) * L_ + l0 + r) * D_ + d] = (bf16)(acc[r] + bval);
      }
    }
  }
}

// ---------------- fused: z@Wpb bias + flash attention, partials over 4 j-chunks ----------------
// grid: bid -> jc = bid&3 (j-chunk of 256), it = (bid>>2)&63 (i-tile of 16), b = bid>>8
// 4 waves: phase A (bias, split by i), phase B (attention, 2 heads per wave)
__global__ __launch_bounds__(256) void fused_attn(
    const float* __restrict__ z, const bf16* __restrict__ qb, const bf16* __restrict__ kb,
    const bf16* __restrict__ vT, const bf16* __restrict__ Wtpb, const int* __restrict__ mask,
    float* __restrict__ part_o, float* __restrict__ part_m, float* __restrict__ part_l) {
  __shared__ _Float16 bias_lds[8 * 16 * 64];   // [h][i][jl], XOR-swizzled
  __shared__ bf16 p_lds_raw[8][16 * 64];       // per (wave,head): rows 16 x 128B, XOR-swizzled
  int bid = blockIdx.x;
  int jc = bid & 3, it = (bid >> 2) & 63, b = bid >> 8;
  int i0 = it * 16, jb = jc * 256;
  int tid = threadIdx.x, w = tid >> 6, lane = tid & 63, lr = lane & 15, lg = lane >> 4;

  bf16x8 wpb0 = *reinterpret_cast<const bf16x8*>(Wtpb + lr * 64 + lg * 8);
  bf16x8 wpb1 = *reinterpret_cast<const bf16x8*>(Wtpb + lr * 64 + 32 + lg * 8);

  const bf16* q0p = qb + ((long)(b * H_ + w * 2 + 0) * L_ + i0 + lr) * D_ + lg * 8;
  const bf16* q1p = qb + ((long)(b * H_ + w * 2 + 1) * L_ + i0 + lr) * D_ + lg * 8;
  bf16x8 qa00 = *reinterpret_cast<const bf16x8*>(q0p);
  bf16x8 qa01 = *reinterpret_cast<const bf16x8*>(q0p + 32);
  bf16x8 qa10 = *reinterpret_cast<const bf16x8*>(q1p);
  bf16x8 qa11 = *reinterpret_cast<const bf16x8*>(q1p + 32);

  const int* mrow = mask + b * L_;
  bool qok[4];
#pragma unroll
  for (int r = 0; r < 4; ++r) qok[r] = mrow[i0 + lg * 4 + r] != 0;

  float mr[2][4], ls[2][4];
  f32x4 o[2][4];
#pragma unroll
  for (int hh = 0; hh < 2; ++hh)
#pragma unroll
    for (int r = 0; r < 4; ++r) {
      mr[hh][r] = -3.0e38f; ls[hh][r] = 0.f;
      o[hh][r] = f32x4{0.f, 0.f, 0.f, 0.f};
    }

  for (int t = 0; t < 4; ++t) {
    int j64 = jb + t * 64;
    // ================= phase A: bias for this j64 tile, waves split i =================
    {
      char* bl = (char*)bias_lds;
      int xo = (lr << 4) ^ (w << 5);            // swizzle const (h = lr)
#pragma unroll
      for (int ii = 0; ii < 4; ++ii) {
        int i = w * 4 + ii;
        const float* zb_ = z + ((long)(b * L_ + i0 + i) * L_ + j64) * 64;
#pragma unroll
        for (int js = 0; js < 4; ++js) {
          const float* zr = zb_ + (js * 16 + lr) * 64 + lg * 8;
          f32x4 f0 = *reinterpret_cast<const f32x4*>(zr);
          f32x4 f1 = *reinterpret_cast<const f32x4*>(zr + 4);
          f32x4 f2 = *reinterpret_cast<const f32x4*>(zr + 32);
          f32x4 f3 = *reinterpret_cast<const f32x4*>(zr + 36);
          bf16x8 a0, a1;
#pragma unroll
          for (int e = 0; e < 4; ++e) {
            a0[e] = (bf16)f0[e]; a0[e + 4] = (bf16)f1[e];
            a1[e] = (bf16)f2[e]; a1[e + 4] = (bf16)f3[e];
          }
          f32x4 c = {0.f, 0.f, 0.f, 0.f};
          c = mfma_bf16(a0, wpb0, c);
          c = mfma_bf16(a1, wpb1, c);
          if (lr < 8) {
            int base = lr * 2048 + i * 128;
#pragma unroll
            for (int r = 0; r < 4; ++r) {
              int jl2 = (js * 16 + lg * 4 + r) * 2;
              *(_Float16*)(bl + base + (jl2 ^ xo)) = (_Float16)c[r];
            }
          }
        }
      }
    }
    __syncthreads();
    // ================= phase B: attention, wave handles heads 2w, 2w+1 =================
#pragma unroll
    for (int hh = 0; hh < 2; ++hh) {
      int h = w * 2 + hh;
      const char* bl = (const char*)bias_lds;
      f32x4 s0, s1, s2, s3;
#pragma unroll
      for (int js = 0; js < 4; ++js) {
        int j = j64 + js * 16 + lr;
        f32x4 acc;
#pragma unroll
        for (int r = 0; r < 4; ++r) {
          int i = lg * 4 + r;
          int byte = h * 2048 + i * 128 + ((((js * 16 + lr) * 2)) ^ (h << 4) ^ (lg << 5));
          acc[r] = (float)*(const _Float16*)(bl + byte);
        }
        const bf16* kr = kb + ((long)(b * H_ + h) * L_ + j) * D_ + lg * 8;
        bf16x8 qf0 = hh == 0 ? qa00 : qa10;
        bf16x8 qf1 = hh == 0 ? qa01 : qa11;
        acc = mfma_bf16(qf0, *reinterpret_cast<const bf16x8*>(kr), acc);
        acc = mfma_bf16(qf1, *reinterpret_cast<const bf16x8*>(kr + 32), acc);
        if (mrow[j] == 0) {
#pragma unroll
          for (int r = 0; r < 4; ++r) acc[r] = NEG_VAL;
        }
        if (js == 0) s0 = acc; else if (js == 1) s1 = acc; else if (js == 2) s2 = acc; else s3 = acc;
      }
#pragma unroll
      for (int r = 0; r < 4; ++r)
        if (!qok[r]) { s0[r] = NEG_VAL; s1[r] = NEG_VAL; s2[r] = NEG_VAL; s3[r] = NEG_VAL; }
      char* pb = (char*)&p_lds_raw[w * 2 + hh][0];
#pragma unroll
      for (int r = 0; r < 4; ++r) {
        float mt_ = fmaxf(fmaxf(s0[r], s1[r]), fmaxf(s2[r], s3[r]));
#pragma unroll
        for (int off = 1; off <= 8; off <<= 1) mt_ = fmaxf(mt_, __shfl_xor(mt_, off));
        float mnew = fmaxf(mr[hh][r], mt_);
        float alpha = __expf(mr[hh][r] - mnew);
        mr[hh][r] = mnew;
        float p0 = __expf(s0[r] - mnew);
        float p1 = __expf(s1[r] - mnew);
        float p2 = __expf(s2[r] - mnew);
        float p3 = __expf(s3[r] - mnew);
        float ps = p0 + p1 + p2 + p3;
#pragma unroll
        for (int off = 1; off <= 8; off <<= 1) ps += __shfl_xor(ps, off);
        ls[hh][r] = ls[hh][r] * alpha + ps;
        o[hh][0][r] *= alpha; o[hh][1][r] *= alpha; o[hh][2][r] *= alpha; o[hh][3][r] *= alpha;
        int row = lg * 4 + r;
        int sw = (row & 7) << 4;
        *(bf16*)(pb + row * 128 + ((lr * 2) ^ sw)) = (bf16)p0;
        *(bf16*)(pb + row * 128 + ((32 + lr * 2) ^ sw)) = (bf16)p1;
        *(bf16*)(pb + row * 128 + ((64 + lr * 2) ^ sw)) = (bf16)p2;
        *(bf16*)(pb + row * 128 + ((96 + lr * 2) ^ sw)) = (bf16)p3;
      }
      int swr = (lr & 7) << 4;
      bf16x8 pa0 = *(const bf16x8*)(pb + lr * 128 + ((lg * 16) ^ swr));
      bf16x8 pa1 = *(const bf16x8*)(pb + lr * 128 + ((64 + lg * 16) ^ swr));
      const bf16* vbb = vT + (long)(b * H_ + h) * D_ * L_;
#pragma unroll
      for (int ds_ = 0; ds_ < 4; ++ds_) {
        const bf16* vr = vbb + (long)(ds_ * 16 + lr) * L_ + j64 + lg * 8;
        f32x4 acc = o[hh][ds_];
        acc = mfma_bf16(pa0, *reinterpret_cast<const bf16x8*>(vr), acc);
        acc = mfma_bf16(pa1, *reinterpret_cast<const bf16x8*>(vr + 32), acc);
        o[hh][ds_] = acc;
      }
    }
    __syncthreads();
  }
  // write partials (unnormalized o, plus m and l)
#pragma unroll
  for (int hh = 0; hh < 2; ++hh) {
    int h = w * 2 + hh;
    long ob = ((long)bid * H_ + h) * 16;
#pragma unroll
    for (int ds_ = 0; ds_ < 4; ++ds_)
#pragma unroll
      for (int r = 0; r < 4; ++r)
        part_o[(ob + lg * 4 + r) * 64 + ds_ * 16 + lr] = o[hh][ds_][r];
    if (lr == 0) {
#pragma unroll
      for (int r = 0; r < 4; ++r) {
        part_m[ob + lg * 4 + r] = mr[hh][r];
        part_l[ob + lg * 4 + r] = ls[hh][r];
      }
    }
  }
}

// ---------------- merge: combine 4 j-chunk partials -> attn_out bf16 ----------------
__global__ __launch_bounds__(256) void merge_kernel(
    const float* __restrict__ part_o, const float* __restrict__ part_m,
    const float* __restrict__ part_l, bf16* __restrict__ attn_out) {
  int t = blockIdx.x * 256 + threadIdx.x;     // 262144 threads
  int d0 = (t & 15) * 4;
  int row = t >> 4;                            // (b,h,i)
  int b = row >> 13, h = (row >> 10) & 7, i = row & 1023;
  int it = i >> 4, il = i & 15;
  float mv[4];
  float M = -3.0e38f;
#pragma unroll
  for (int jcx = 0; jcx < 4; ++jcx) {
    int bid = (b * 64 + it) * 4 + jcx;
    mv[jcx] = part_m[((long)bid * H_ + h) * 16 + il];
    M = fmaxf(M, mv[jcx]);
  }
  float lt = 0.f;
  float oa[4] = {0.f, 0.f, 0.f, 0.f};
#pragma unroll
  for (int jcx = 0; jcx < 4; ++jcx) {
    int bid = (b * 64 + it) * 4 + jcx;
    long base = (long)bid * H_ * 16 + (long)h * 16 + il;
    float c = __expf(mv[jcx] - M);
    lt += c * part_l[base];
    f32x4 ov = *reinterpret_cast<const f32x4*>(part_o + base * 64 + d0);
#pragma unroll
    for (int e = 0; e < 4; ++e) oa[e] += c * ov[e];
  }
  float inv = 1.0f / lt;
  bf16x4 r_;
#pragma unroll
  for (int e = 0; e < 4; ++e) r_[e] = (bf16)(oa[e] * inv);
  *reinterpret_cast<bf16x4*>(attn_out + ((long)(b * L_ + i)) * DM_ + h * D_ + d0) = r_;
}

// ---------------- out: attn_out(2048x512) @ Wto^T -> d_out fp32 + bo ----------------
__global__ __launch_bounds__(256) void out_gemm(
    const bf16* __restrict__ ab, const bf16* __restrict__ Wto,
    const float* __restrict__ bo, float* __restrict__ out) {
  int wid = blockIdx.x * 4 + (threadIdx.x >> 6);
  int lane = threadIdx.x & 63;
  int mt = wid >> 4, nt = wid & 15;    // 64 x 16 tiles of 32x32
  int row0 = mt * 32, col0 = nt * 32;
  int lr = lane & 15, lg = lane >> 4;
  const bf16* a0p = ab + (row0 + lr) * 512 + lg * 8;
  const bf16* a1p = a0p + 16 * 512;
  const bf16* b0p = Wto + (col0 + lr) * 512 + lg * 8;
  const bf16* b1p = b0p + 16 * 512;
  f32x4 acc00 = {0.f,0.f,0.f,0.f}, acc01 = acc00, acc10 = acc00, acc11 = acc00;
#pragma unroll
  for (int kk = 0; kk < 512; kk += 32) {
    bf16x8 a0 = *reinterpret_cast<const bf16x8*>(a0p + kk);
    bf16x8 a1 = *reinterpret_cast<const bf16x8*>(a1p + kk);
    bf16x8 b0 = *reinterpret_cast<const bf16x8*>(b0p + kk);
    bf16x8 b1 = *reinterpret_cast<const bf16x8*>(b1p + kk);
    acc00 = mfma_bf16(a0, b0, acc00);
    acc01 = mfma_bf16(a0, b1, acc01);
    acc10 = mfma_bf16(a1, b0, acc10);
    acc11 = mfma_bf16(a1, b1, acc11);
  }
#pragma unroll
  for (int ni = 0; ni < 2; ++ni) {
    int col = col0 + ni * 16 + lr;
    float bval = bo[col];
#pragma unroll
    for (int mi = 0; mi < 2; ++mi) {
      f32x4 acc = (mi == 0) ? (ni == 0 ? acc00 : acc01) : (ni == 0 ? acc10 : acc11);
      int m0 = row0 + mi * 16 + lg * 4;
#pragma unroll
      for (int r = 0; r < 4; ++r) out[(long)(m0 + r) * 512 + col] = acc[r] + bval;
    }
  }
}

extern "C" void kernel_launch(void* const* d_in, const int* in_sizes, int n_in,
                              void* d_out, int out_size, void* d_ws, size_t ws_size,
                              hipStream_t stream) {
  const float* x    = (const float*)d_in[0];
  const float* z    = (const float*)d_in[1];
  const int*   mask = (const int*)d_in[2];
  const float* Wq   = (const float*)d_in[3];
  const float* bq   = (const float*)d_in[4];
  const float* Wk   = (const float*)d_in[5];
  const float* bk   = (const float*)d_in[6];
  const float* Wv   = (const float*)d_in[7];
  const float* bv   = (const float*)d_in[8];
  const float* Wo   = (const float*)d_in[9];
  const float* bo   = (const float*)d_in[10];
  const float* Wpb  = (const float*)d_in[11];

  char* ws = (char*)d_ws;
  bf16* xb        = (bf16*)(ws + 0);                    // 2 MB
  bf16* Wt        = (bf16*)(ws + 2097152);              // 1.5 MB
  bf16* Wto       = (bf16*)(ws + 3670016);              // 0.5 MB
  bf16* Wtpb      = (bf16*)(ws + 4194304);              // 2 KB
  bf16* qbuf      = (bf16*)(ws + 4196352);              // 2 MB
  bf16* kbuf      = (bf16*)(ws + 6293504);              // 2 MB
  bf16* vTbuf     = (bf16*)(ws + 8390656);              // 2 MB
  bf16* attn_out  = (bf16*)(ws + 10487808);             // 2 MB
  float* part_o   = (float*)(ws + 12584960);            // 16.78 MB
  float* part_m   = (float*)(ws + 29362176);            // 256 KB
  float* part_l   = (float*)(ws + 29624320);            // 256 KB -> ~28.5 MB total

  prep_kernel<<<2048, 256, 0, stream>>>(x, Wq, Wk, Wv, Wo, Wpb, xb, Wt, Wto, Wtpb);
  qkv_gemm<<<768, 256, 0, stream>>>(xb, Wt, bq, bk, bv, qbuf, kbuf, vTbuf);
  fused_attn<<<512, 256, 0, stream>>>(z, qbuf, kbuf, vTbuf, Wtpb, mask, part_o, part_m, part_l);
  merge_kernel<<<1024, 256, 0, stream>>>(part_o, part_m, part_l, attn_out);
  out_gemm<<<256, 256, 0, stream>>>(attn_out, Wto, bo, (float*)d_out);
}